// Round 3
// baseline (305.540 us; speedup 1.0000x reference)
//
#include <hip/hip_runtime.h>
#include <hip/hip_bf16.h>

// Problem constants (match reference)
#define BATCH   8
#define CDIM    256
#define ODIM    16
#define GRID16  16
#define NCELL   4096            // 16*16*16
#define PADW    17
#define PADV    (PADW*PADW*PADW)
#define MAXK    32              // point chunks per batch (256 blocks total)
#define SENT16  0x007Fu         // mapped bf16 -inf
#define SENTPK  0x007F007Fu

// ws layout (u32 words):
//   [0, 1024)      : W1b1 packed float4 per c  (w1,w1,w1,b1)
//   [1024, 3072)   : W2 bf16 MFMA B-fragments  (kt*64+lane)*4 u32
//   [4096, ...)    : Km * BATCH slabs of 8*4096 packed-bf16-pair u32
#define HDR_WORDS   4096
#define SLAB_WORDS  (8 * 4096)   // 32768 u32 = 128 KiB

typedef __attribute__((ext_vector_type(8))) short bf16x8;
typedef __attribute__((ext_vector_type(4))) float f32x4;

// ---------------------------------------------------------------------------
// monotone bf16(u16) <-> mapped-u16 so unsigned max == float max
__device__ __forceinline__ unsigned map16(unsigned r) {
    return (r ^ ((r & 0x8000u) ? 0xFFFFu : 0x8000u)) & 0xFFFFu;
}
__device__ __forceinline__ float unmap16(unsigned m) {
    unsigned r = (m & 0x8000u) ? (m ^ 0x8000u) : (~m & 0xFFFFu);
    return __uint_as_float(r << 16);
}

// fp32 -> bf16 bits, RTNE
__device__ __forceinline__ unsigned bf16rtne(float v) {
    unsigned u = __float_as_uint(v);
    return (u + 0x7FFFu + ((u >> 16) & 1u)) >> 16;
}

// ---------------------------------------------------------------------------
__global__ void k_pack2(const float* __restrict__ W1, const float* __restrict__ b1,
                        const float* __restrict__ W2, unsigned* __restrict__ ws) {
    int t = threadIdx.x;                    // 512 threads
    float* w1p = reinterpret_cast<float*>(ws);
    if (t < 256) {
        float4 v;
        v.x = W1[t * 3 + 0];
        v.y = W1[t * 3 + 1];
        v.z = W1[t * 3 + 2];
        v.w = b1[t];
        reinterpret_cast<float4*>(w1p)[t] = v;
    }
    // B fragments: lane l holds n = l&15, k-slots j -> c = kt*32 + (l>>4)*8 + j
    int kt = t >> 6, l = t & 63;
    int lg = l >> 4, o = l & 15;
    int cb = kt * 32 + lg * 8;
    unsigned w[4];
#pragma unroll
    for (int i = 0; i < 4; ++i) {
        float f0 = W2[o * CDIM + cb + 2 * i];
        float f1 = W2[o * CDIM + cb + 2 * i + 1];
        __hip_bfloat162 bb = __float22bfloat162_rn(make_float2(f0, f1));
        unsigned u; __builtin_memcpy(&u, &bb, 4);
        w[i] = u;
    }
    uint4 q; q.x = w[0]; q.y = w[1]; q.z = w[2]; q.w = w[3];
    reinterpret_cast<uint4*>(ws + 1024)[t] = q;
}

// ---------------------------------------------------------------------------
// per-field (2x bf16-mapped u16) max via CAS; low contention expected
__device__ __forceinline__ void casmax(unsigned* addr, unsigned wv) {
    unsigned cur = *addr;
    while (true) {
        unsigned nh = max(cur >> 16, wv >> 16);
        unsigned nl = max(cur & 0xFFFFu, wv & 0xFFFFu);
        unsigned nv = (nh << 16) | nl;
        if (nv == cur) return;
        unsigned prev = atomicCAS(addr, cur, nv);
        if (prev == cur) return;
        cur = prev;
    }
}

// ---------------------------------------------------------------------------
// MFMA scatter: block (k, b). 16 waves; each wave does 2x 16-point M-tiles
// per iteration. LDS grid: cm[8][4096] packed bf16 pairs (ch 2w | ch 2w+1<<16).
__global__ __launch_bounds__(1024, 4)
void k_scatter_mfma(const float* __restrict__ xin,
                    const unsigned* __restrict__ ws,
                    const float* __restrict__ b2,
                    unsigned* __restrict__ slabs,
                    int nper, int chunk) {
    __shared__ unsigned cm[SLAB_WORDS];      // 128 KiB
    __shared__ float4 w1s[256];              // 4 KiB
    const int kblk = blockIdx.x, b = blockIdx.z;
    const int tid = threadIdx.x;
    const int l = tid & 63, wv = tid >> 6;   // lane, wave
    const int lg = l >> 4;

    if (tid < 256)
        w1s[tid] = reinterpret_cast<const float4*>(ws)[tid];
    for (int i = tid; i < SLAB_WORDS; i += 1024) cm[i] = SENTPK;

    // W2 B-fragments into registers (32 VGPR)
    bf16x8 w2f[8];
#pragma unroll
    for (int kt = 0; kt < 8; ++kt) {
        uint4 q = reinterpret_cast<const uint4*>(ws + 1024)[kt * 64 + l];
        union { uint4 q; bf16x8 v; } cv; cv.q = q;
        w2f[kt] = cv.v;
    }
    float b2v = b2[l & 15];
    __syncthreads();

    const int p0 = kblk * chunk;
    const int p1 = min(p0 + chunk, nper);
    const float* xb = xin + (size_t)b * nper * 3;

    for (int gb = p0 + wv * 32; gb < p1; gb += 1024 / 64 * 32) {
        // ---- load x for 2 tiles (16 pts each) ----
        int ptA = gb + (l & 15);
        int ptB = gb + 16 + (l & 15);
        int pa = min(ptA, nper - 1), pb = min(ptB, nper - 1);
        float ax = xb[pa * 3 + 0], ay = xb[pa * 3 + 1], az = xb[pa * 3 + 2];
        float bx = xb[pb * 3 + 0], by = xb[pb * 3 + 1], bz = xb[pb * 3 + 2];
        int cellA = ((min(max((int)floorf(ax), 0), 15) << 8) |
                     (min(max((int)floorf(ay), 0), 15) << 4) |
                      min(max((int)floorf(az), 0), 15));
        int cellB = ((min(max((int)floorf(bx), 0), 15) << 8) |
                     (min(max((int)floorf(by), 0), 15) << 4) |
                      min(max((int)floorf(bz), 0), 15));

        f32x4 accA = {0.f, 0.f, 0.f, 0.f};
        f32x4 accB = {0.f, 0.f, 0.f, 0.f};
#pragma unroll
        for (int kt = 0; kt < 8; ++kt) {
            int cb = kt * 32 + lg * 8;
            unsigned ua[4], ub[4];
#pragma unroll
            for (int i = 0; i < 4; ++i) {
                float4 w0 = w1s[cb + 2 * i];
                float4 w1 = w1s[cb + 2 * i + 1];
                float hA0 = fmaxf(fmaf(w0.x, ax, fmaf(w0.y, ay, fmaf(w0.z, az, w0.w))), 0.f);
                float hA1 = fmaxf(fmaf(w1.x, ax, fmaf(w1.y, ay, fmaf(w1.z, az, w1.w))), 0.f);
                float hB0 = fmaxf(fmaf(w0.x, bx, fmaf(w0.y, by, fmaf(w0.z, bz, w0.w))), 0.f);
                float hB1 = fmaxf(fmaf(w1.x, bx, fmaf(w1.y, by, fmaf(w1.z, bz, w1.w))), 0.f);
                __hip_bfloat162 ha = __float22bfloat162_rn(make_float2(hA0, hA1));
                __hip_bfloat162 hb = __float22bfloat162_rn(make_float2(hB0, hB1));
                __builtin_memcpy(&ua[i], &ha, 4);
                __builtin_memcpy(&ub[i], &hb, 4);
            }
            union { unsigned u[4]; bf16x8 v; } avA, avB;
#pragma unroll
            for (int i = 0; i < 4; ++i) { avA.u[i] = ua[i]; avB.u[i] = ub[i]; }
            accA = __builtin_amdgcn_mfma_f32_16x16x32_bf16(avA.v, w2f[kt], accA, 0, 0, 0);
            accB = __builtin_amdgcn_mfma_f32_16x16x32_bf16(avB.v, w2f[kt], accB, 0, 0, 0);
        }

        // ---- epilogue per tile: +b2, bf16-map, pack pairs, CAS into cm ----
#pragma unroll
        for (int tile = 0; tile < 2; ++tile) {
            f32x4 acc = tile ? accB : accA;
            int cell16 = tile ? cellB : cellA;
            int gbase = gb + tile * 16;

            unsigned m[4];
#pragma unroll
            for (int j = 0; j < 4; ++j)
                m[j] = map16(bf16rtne(acc[j] + b2v));

            unsigned pk01 = m[0] | (m[1] << 16);
            unsigned pk23 = m[2] | (m[3] << 16);
            unsigned q01 = __shfl_xor(pk01, 1);
            unsigned q23 = __shfl_xor(pk23, 1);
            int half = l & 1;
            unsigned aown = half ? pk23 : pk01;
            unsigned apar = half ? q23 : q01;
            unsigned losrc = half ? apar : aown;   // even channel -> lo
            unsigned hisrc = half ? aown : apar;   // odd channel  -> hi
            unsigned wA = (losrc & 0xFFFFu) | ((hisrc & 0xFFFFu) << 16);
            unsigned wB = (losrc >> 16) | (hisrc & 0xFFFF0000u);
            int r0 = lg * 4 + half * 2;
            int cA = __shfl(cell16, r0);
            int cB = __shfl(cell16, r0 + 1);
            unsigned op = (l >> 1) & 7;
            if (gbase + r0 < p1)     casmax(&cm[op * 4096 + cA], wA);
            if (gbase + r0 + 1 < p1) casmax(&cm[op * 4096 + cB], wB);
        }
    }
    __syncthreads();

    // flush slab
    unsigned* dst = slabs + (size_t)(kblk * BATCH + b) * SLAB_WORDS;
    uint4* d4 = reinterpret_cast<uint4*>(dst);
    const uint4* s4 = reinterpret_cast<const uint4*>(cm);
    for (int i = tid; i < SLAB_WORDS / 4; i += 1024) d4[i] = s4[i];
}

// ---------------------------------------------------------------------------
// reduce K slabs -> out interior. thread = (b, word, cell), 2 channels each.
__global__ __launch_bounds__(256)
void k_reduce2(const unsigned* __restrict__ slabs, float* __restrict__ out, int K) {
    int t = blockIdx.x * 256 + threadIdx.x;
    if (t >= BATCH * 8 * NCELL) return;
    int cell = t & (NCELL - 1);
    int op = (t >> 12) & 7;
    int b = t >> 15;

    unsigned ml = SENT16, mh = SENT16;
#pragma unroll 4
    for (int k = 0; k < K; ++k) {
        unsigned w = slabs[(size_t)(k * BATCH + b) * SLAB_WORDS + op * 4096 + cell];
        ml = max(ml, w & 0xFFFFu);
        mh = max(mh, w >> 16);
    }
    int ix = cell >> 8, iy = (cell >> 4) & 15, iz = cell & 15;
    size_t obase = ((size_t)b * ODIM + op * 2) * PADV + ((ix * PADW + iy) * PADW + iz);
    out[obase]        = (ml == SENT16) ? 0.0f : unmap16(ml);
    out[obase + PADV] = (mh == SENT16) ? 0.0f : unmap16(mh);
}

// ===========================================================================
// Fallback (round-1): direct global atomics. Used only if ws too small.
__global__ void k_init(unsigned* __restrict__ out, int total) {
    int i = blockIdx.x * blockDim.x + threadIdx.x;
    if (i >= total) return;
    int r = i % PADV;
    int z = r % PADW, y = (r / PADW) % PADW, x = r / (PADW * PADW);
    out[i] = (x < GRID16 && y < GRID16 && z < GRID16) ? 0xFF800000u : 0u;
}
__device__ __forceinline__ void atomicMaxFloat(float* addr, float v) {
    if (v >= 0.0f) atomicMax(reinterpret_cast<int*>(addr), __float_as_int(v));
    else           atomicMin(reinterpret_cast<unsigned*>(addr), __float_as_uint(v));
}
__global__ __launch_bounds__(256)
void k_scatter_glb(const float* __restrict__ xin,
                   const float* __restrict__ W1, const float* __restrict__ b1,
                   const float* __restrict__ W2, const float* __restrict__ b2,
                   float* __restrict__ out, int npts, int nper) {
    int p = blockIdx.x * 256 + threadIdx.x;
    if (p >= npts) return;
    float x0 = xin[p*3+0], x1 = xin[p*3+1], x2 = xin[p*3+2];
    float acc[ODIM];
#pragma unroll
    for (int o = 0; o < ODIM; ++o) acc[o] = b2[o];
#pragma unroll 2
    for (int c = 0; c < CDIM; ++c) {
        float h = fmaf(W1[c*3+0], x0, fmaf(W1[c*3+1], x1, fmaf(W1[c*3+2], x2, b1[c])));
        h = fmaxf(h, 0.0f);
#pragma unroll
        for (int o = 0; o < ODIM; ++o) acc[o] = fmaf(W2[o*CDIM+c], h, acc[o]);
    }
    int ix = min(max((int)floorf(x0), 0), GRID16-1);
    int iy = min(max((int)floorf(x1), 0), GRID16-1);
    int iz = min(max((int)floorf(x2), 0), GRID16-1);
    int b = p / nper;
    size_t base = ((((size_t)b*ODIM)*PADW + ix)*PADW + iy)*PADW + iz;
#pragma unroll
    for (int o = 0; o < ODIM; ++o)
        atomicMaxFloat(out + base + (size_t)o*PADV, acc[o]);
}
__global__ void k_final(unsigned* __restrict__ out, int total) {
    int i = blockIdx.x * blockDim.x + threadIdx.x;
    if (i >= total) return;
    if (out[i] == 0xFF800000u) out[i] = 0u;
}

// ===========================================================================
extern "C" void kernel_launch(void* const* d_in, const int* in_sizes, int n_in,
                              void* d_out, int out_size, void* d_ws, size_t ws_size,
                              hipStream_t stream) {
    const float* x  = (const float*)d_in[0];
    const float* W1 = (const float*)d_in[1];
    const float* b1 = (const float*)d_in[2];
    const float* W2 = (const float*)d_in[3];
    const float* b2 = (const float*)d_in[4];
    float* out = (float*)d_out;

    int npts = in_sizes[0] / 3;          // B*N
    int nper = npts / BATCH;             // N

    size_t ws_words = ws_size / 4;
    int Km = 0;
    if (ws_words > HDR_WORDS) {
        size_t avail = (ws_words - HDR_WORDS) / ((size_t)BATCH * SLAB_WORDS);
        Km = (int)min((size_t)MAXK, avail);
    }

    if (Km >= 1) {
        unsigned* ws = (unsigned*)d_ws;
        k_pack2<<<1, 512, 0, stream>>>(W1, b1, W2, ws);
        hipMemsetAsync(d_out, 0, (size_t)out_size * sizeof(float), stream);

        unsigned* slabs = ws + HDR_WORDS;
        int chunk = (nper + Km - 1) / Km;
        dim3 grid(Km, 1, BATCH);
        k_scatter_mfma<<<grid, 1024, 0, stream>>>(x, ws, b2, slabs, nper, chunk);

        int rt = BATCH * 8 * NCELL;
        k_reduce2<<<(rt + 255) / 256, 256, 0, stream>>>(slabs, out, Km);
    } else {
        int total = out_size;
        k_init<<<(total + 255) / 256, 256, 0, stream>>>((unsigned*)out, total);
        int blocks = (npts + 255) / 256;
        k_scatter_glb<<<blocks, 256, 0, stream>>>(x, W1, b1, W2, b2, out, npts, nper);
        k_final<<<(total + 255) / 256, 256, 0, stream>>>((unsigned*)out, total);
    }
}